// Round 11
// baseline (3366.252 us; speedup 1.0000x reference)
//
#include <hip/hip_runtime.h>
#include <math.h>

#define NB 16
#define NR 100
#define NV 50000
#define ND 1024
#define NT 20
#define VP1 50001
#define VP1R 50004     // logits row stride (float4-aligned)
#define VPAD 50016     // padded Wl / partL row stride
#define VTT 50101
#define RP1 101
#define NEGF (-1e10f)
#define NSLICE 13
#define LSE_T 13
#define KS1 8          // k1 k-groups (128 k each)
#define K5SPLIT 64
#define EN_WORD (NSLICE*NB*16)    // 3328
#define EN_TOT  (EN_WORD + NB*NR) // 4928
#define F4ROW (VPAD/4)            // 12504 float4 per padded row

struct P {
  const float* embed; const float* Wx; const float* Wh; const float* Wc;
  const float* Wl; const float* Wd; const float* rnn0; const float* det0;
  const float* h0; const float* pool; const float* ppls; const float* pnt;
  float* WlP;      // [1024][VPAD]
  float* logits;   // [16][VP1R]
  float* dlp;      // [16][101]
  float* rnnT;     // [1024][16]
  float* hst;      // [16][1024]
  float* hhgT;     // [1024][16]
  float* xtT;      // [1024][16]
  float* ctxT;     // [1024][16]
  float* mask0; float* mask1;       // [16][101] ping-pong
  int* bs0; int* bs1;               // [20][16] ping-pong
  float* blp0; float* blp1;         // [20][16] ping-pong
  float* lp0; float* lp1;           // [16]
  float* pkv; unsigned* pkf;        // [EN_WORD]
  float* part;     // [K5SPLIT][16][1024]
  float* partL;    // [KS1][16][VPAD]
  float* blkM; float* blkS;         // [16*13]
};

__device__ __forceinline__ bool better(float av, unsigned af, float bv, unsigned bf){
  return (av > bv) || (av == bv && af < bf);
}
__device__ __forceinline__ void lsecomb(float& m, float& s, float m2, float s2){
  float M = fmaxf(m, m2);
  if (M == -INFINITY){ m = M; s = 0.f; return; }
  s = s*expf(m - M) + s2*expf(m2 - M);
  m = M;
}

// ---------------- K0: init ----------------
__global__ __launch_bounds__(256) void k0_init(P p){
  int i = blockIdx.x*256 + threadIdx.x;
  int n = gridDim.x*256;
  for (int o=i; o<NB*ND; o+=n){ int b=o>>10, k=o&1023; p.rnnT[k*NB+b] = p.rnn0[o]; }
  for (int o=i; o<NT*NB; o+=n){ p.bs0[o]=0; p.bs1[o]=0; p.blp0[o]=0.f; p.blp1[o]=0.f; }
  for (int o=i; o<NB; o+=n){ p.lp0[o]=0.f; p.lp1[o]=0.f; }
}

// ------- K0b: pad Wl -> WlP (flat f4 over dst, aligned f4 stores) -----------
__global__ __launch_bounds__(256) void k0_pad(const float* __restrict__ Wl,
                                              float* __restrict__ WlP){
  const int TOT = ND * F4ROW;           // 12,804,096 dst float4s
  int idx0 = blockIdx.x*256 + threadIdx.x;
  int stride = gridDim.x*256;
  float4* dst = reinterpret_cast<float4*>(WlP);
  for (int idx = idx0; idx < TOT; idx += stride){
    int k = idx / F4ROW;
    int j = (idx - k*F4ROW) * 4;
    const float* src = Wl + (size_t)k*VP1 + j;
    float4 v;
    v.x = (j   < VP1) ? src[0] : 0.f;
    v.y = (j+1 < VP1) ? src[1] : 0.f;
    v.z = (j+2 < VP1) ? src[2] : 0.f;
    v.w = (j+3 < VP1) ? src[3] : 0.f;
    dst[(size_t)k*F4ROW + (j>>2)] = v;
  }
}

// ---------------- K1: partial logits = rnn_out @ WlP (float4 columns) -------
// grid (8, 49) x 256 thr: one float4 col-group/thread, 128 k per group,
// 8-deep double-buffered float4 batches, 8 KB LDS rnnT slice.
__global__ __launch_bounds__(256) void k1_logits(const float* __restrict__ WlP,
    const float* __restrict__ rnnT, float* __restrict__ partL){
  __shared__ float rlds[128*16];     // 8 KB
  int tid = threadIdx.x;
  int g = blockIdx.x;                // 0..7
  int jt = blockIdx.y;               // 0..48
  int k0 = g*128;
  const float4* r4 = reinterpret_cast<const float4*>(rnnT) + (size_t)k0*4;
  float4* l4 = reinterpret_cast<float4*>(rlds);
  l4[tid] = r4[tid];
  l4[256+tid] = r4[256+tid];
  __syncthreads();
  int j4 = jt*1024 + tid*4;
  bool ok = (j4 < VPAD);
  const float4* wp = reinterpret_cast<const float4*>(
      WlP + (size_t)k0*VPAD + (ok ? j4 : 0));
  const size_t wstr = F4ROW;
  if (ok){
    float4 acc[16];
    #pragma unroll
    for (int b=0;b<16;++b) acc[b] = make_float4(0.f,0.f,0.f,0.f);
    float4 wa[8], wb[8];
    #define LD8F(karr, kb) { \
      _Pragma("unroll") \
      for (int u=0;u<8;++u) karr[u] = wp[(size_t)((kb)+u)*wstr]; \
      }
    #define FMA8F(karr, kb) { \
      _Pragma("unroll") \
      for (int u=0;u<8;++u){ \
        const float* rr = &rlds[((kb)+u)*16]; \
        float4 wv = karr[u]; \
        _Pragma("unroll") \
        for (int b=0;b<16;++b){ \
          float r = rr[b]; \
          acc[b].x = fmaf(r, wv.x, acc[b].x); \
          acc[b].y = fmaf(r, wv.y, acc[b].y); \
          acc[b].z = fmaf(r, wv.z, acc[b].z); \
          acc[b].w = fmaf(r, wv.w, acc[b].w); \
        } \
      } }
    LD8F(wa, 0);
    #pragma unroll 1
    for (int bt=0; bt<8; ++bt){
      LD8F(wb, bt*16+8);
      FMA8F(wa, bt*16);
      if (bt < 7){ LD8F(wa, bt*16+16); }
      FMA8F(wb, bt*16+8);
    }
    #undef LD8F
    #undef FMA8F
    float4* pb = reinterpret_cast<float4*>(partL) + (size_t)(g*16)*wstr + (j4>>2);
    #pragma unroll
    for (int b=0;b<16;++b) pb[(size_t)b*wstr] = acc[b];
  }
}

// --- K2: sum partials -> logits + slice LSE partial + raw top16 (+det@slice0)
__global__ __launch_bounds__(256) void k2_sum_topk(P p, int t){
  int slice = blockIdx.x, b = blockIdx.y, tid = threadIdx.x;
  const size_t pstride = F4ROW;
  const size_t lstride = VP1R/4;
  const float4* base = reinterpret_cast<const float4*>(p.partL);
  float4* lg4 = reinterpret_cast<float4*>(p.logits);
  float lv[16]; unsigned lf[16];
  unsigned fbase = (unsigned)(b*VTT);
  float m = -INFINITY, s = 0.f;
  int j0 = slice*4096 + tid*4;
  #pragma unroll
  for (int c=0;c<4;++c){
    int j = j0 + c*1024;
    float vals[4] = {0.f,0.f,0.f,0.f};
    bool any = (j < VP1);
    if (any){
      size_t jq = (size_t)(j >> 2);
      float4 sm = make_float4(0,0,0,0);
      #pragma unroll
      for (int g=0; g<KS1; ++g){
        float4 a = base[(size_t)(g*16+b)*pstride + jq];
        sm.x += a.x; sm.y += a.y; sm.z += a.z; sm.w += a.w;
      }
      lg4[(size_t)b*lstride + jq] = sm;
      vals[0]=sm.x; vals[1]=sm.y; vals[2]=sm.z; vals[3]=sm.w;
    }
    #pragma unroll
    for (int e=0;e<4;++e){
      int jj = j + e;
      if (any && jj < VP1){
        float x = vals[e];
        if (x > m){ s = s*expf(m-x) + 1.f; m = x; }
        else s += expf(x-m);
        lv[c*4+e] = x; lf[c*4+e] = fbase + (unsigned)jj;
      } else { lv[c*4+e] = -3e38f; lf[c*4+e] = 0xFFFFFFFFu; }
    }
  }
  #pragma unroll
  for (int off=32; off; off>>=1){
    float m2 = __shfl_down(m, off), s2 = __shfl_down(s, off);
    lsecomb(m, s, m2, s2);
  }
  __shared__ float wm[4], ws2[4];
  int lane = tid & 63, wid = tid >> 6;
  if (lane == 0){ wm[wid] = m; ws2[wid] = s; }
  __syncthreads();
  if (tid == 0){
    float M = wm[0], S = ws2[0];
    lsecomb(M, S, wm[1], ws2[1]);
    lsecomb(M, S, wm[2], ws2[2]);
    lsecomb(M, S, wm[3], ws2[3]);
    p.blkM[b*LSE_T + slice] = M; p.blkS[b*LSE_T + slice] = S;
  }
  __shared__ float wmv[4]; __shared__ unsigned wmf[4];
  __shared__ unsigned sbf;
  int blin = b*NSLICE + slice;
  for (int r=0;r<16;++r){
    float bv = lv[0]; unsigned bf = lf[0];
    #pragma unroll
    for (int u=1;u<16;++u) if (better(lv[u],lf[u],bv,bf)){ bv=lv[u]; bf=lf[u]; }
    #pragma unroll
    for (int off=32; off; off>>=1){
      float ov = __shfl_down(bv, off); unsigned of = __shfl_down(bf, off);
      if (better(ov,of,bv,bf)){ bv=ov; bf=of; }
    }
    if (lane==0){ wmv[wid]=bv; wmf[wid]=bf; }
    __syncthreads();
    if (tid==0){
      float mv2=wmv[0]; unsigned mf2=wmf[0];
      #pragma unroll
      for (int w=1;w<4;++w) if (better(wmv[w],wmf[w],mv2,mf2)){ mv2=wmv[w]; mf2=wmf[w]; }
      p.pkv[blin*16+r]=mv2; p.pkf[blin*16+r]=mf2;
      sbf=mf2;
    }
    __syncthreads();
    unsigned WF = sbf;
    #pragma unroll
    for (int u=0;u<16;++u) if (lf[u]==WF){ lv[u]=-3e38f; lf[u]=0xFFFFFFFFu; }
  }
  // det head + dlp (slice-0 blocks only)
  if (slice == 0){
    __shared__ float dred[2][129];
    __shared__ float ddet[128];
    int jj = tid & 127, ks2 = tid >> 7;
    if (t == 0){
      if (tid < 128) ddet[tid] = (tid < RP1) ? p.det0[b*RP1 + tid] : -INFINITY;
      __syncthreads();
    } else {
      float a = 0.f;
      if (jj < RP1){
        const float* hr = p.hst + b*ND;
        for (int k=ks2*512; k<ks2*512+512; ++k)
          a = fmaf(hr[k], p.Wd[(size_t)k*RP1 + jj], a);
      }
      dred[ks2][jj] = a;
      __syncthreads();
      if (tid < 128)
        ddet[tid] = (tid < RP1) ? (dred[0][tid] + dred[1][tid]) : -INFINITY;
      __syncthreads();
    }
    if (tid < 64){
      float a = ddet[tid], a2 = ddet[tid+64];
      float mm = fmaxf(a, a2);
      #pragma unroll
      for (int off=32; off; off>>=1) mm = fmaxf(mm, __shfl_down(mm, off));
      mm = __shfl(mm, 0);
      float e1 = (tid < RP1) ? expf(a - mm) : 0.f;
      float e2 = (tid+64 < RP1) ? expf(a2 - mm) : 0.f;
      float ss = e1 + e2;
      #pragma unroll
      for (int off=32; off; off>>=1) ss += __shfl_down(ss, off);
      ss = __shfl(ss, 0);
      float ls = logf(ss);
      if (tid < RP1)     p.dlp[b*RP1 + tid]      = a  - mm - ls;
      if (tid+64 < RP1)  p.dlp[b*RP1 + tid + 64] = a2 - mm - ls;
    }
  }
}

// ---- K4: lse + merge + beam state + attention + ctx, fused (16 x 1024) -----
__global__ __launch_bounds__(1024) void k4_beam(P p, int t){
  int bi = blockIdx.x, tid = threadIdx.x;
  const float* lpin  = (t&1)? p.lp1 : p.lp0;
  float*       lpout = (t&1)? p.lp0 : p.lp1;
  __shared__ float lseS[16], lpS[16], dlp0S[16];
  __shared__ float hhs[ND];
  __shared__ float att[128];
  __shared__ float msk[RP1];
  if (tid < 16){
    float m = p.blkM[tid*LSE_T], s = p.blkS[tid*LSE_T];
    #pragma unroll
    for (int u=1;u<LSE_T;++u) lsecomb(m, s, p.blkM[tid*LSE_T+u], p.blkS[tid*LSE_T+u]);
    lseS[tid] = m + logf(s);
    lpS[tid] = lpin[tid];
    dlp0S[tid] = p.dlp[tid*RP1];
  }
  __syncthreads();
  float ev[5]; unsigned ef[5];
  #pragma unroll
  for (int c=0;c<5;++c){
    int idx = c*1024 + tid;
    float v = -3e38f; unsigned f = 0xFFFFFFFFu;
    if (idx < EN_WORD){
      f = p.pkf[idx];
      if (f != 0xFFFFFFFFu){
        unsigned q = f / VTT;
        float raw = p.pkv[idx];
        v = (t==0 && q>0) ? NEGF : (lpS[q] + ((raw - lseS[q]) + dlp0S[q]));
      }
    } else if (idx < EN_TOT){
      int i2 = idx - EN_WORD;
      int q = i2 / NR, r = i2 - q*NR;
      f = (unsigned)(q*VTT + VP1 + r);
      v = (t==0 && q>0) ? NEGF : (lpS[q] + p.dlp[q*RP1 + r + 1]);
    }
    ev[c]=v; ef[c]=f;
  }
  __shared__ float wmv[16]; __shared__ unsigned wmf[16];
  __shared__ unsigned sbf;
  __shared__ int wq[16], wc[16]; __shared__ float wvv[16];
  __shared__ int s_q, s_it; __shared__ float s_local;
  int lane = tid & 63, wid = tid >> 6;
  for (int r=0;r<16;++r){
    float bv = ev[0]; unsigned bf = ef[0];
    #pragma unroll
    for (int c=1;c<5;++c) if (better(ev[c],ef[c],bv,bf)){ bv=ev[c]; bf=ef[c]; }
    #pragma unroll
    for (int off=32; off; off>>=1){
      float ov = __shfl_down(bv, off); unsigned of = __shfl_down(bf, off);
      if (better(ov,of,bv,bf)){ bv=ov; bf=of; }
    }
    if (lane==0){ wmv[wid]=bv; wmf[wid]=bf; }
    __syncthreads();
    if (tid==0){
      float mv2=wmv[0]; unsigned mf2=wmf[0];
      #pragma unroll
      for (int w=1;w<16;++w) if (better(wmv[w],wmf[w],mv2,mf2)){ mv2=wmv[w]; mf2=wmf[w]; }
      unsigned q = mf2 / VTT; unsigned c = mf2 - q*VTT;
      wq[r]=(int)q; wc[r]=(int)c; wvv[r]=mv2;
      sbf=mf2;
    }
    __syncthreads();
    unsigned WF = sbf;
    #pragma unroll
    for (int c=0;c<5;++c) if (ef[c]==WF){ ev[c]=-3e38f; ef[c]=0xFFFFFFFFu; }
  }
  if (tid == 0){
    int q = wq[bi], c = wc[bi];
    float local = (c < VP1) ? ((p.logits[(size_t)q*VP1R + c] - lseS[q]) + dlp0S[q])
                            : p.dlp[q*RP1 + (c - NV)];
    int it = (c > NV) ? ((int)p.ppls[((size_t)bi*NR + (c - VP1))*6 + 4] + NV) : c;
    s_q = q; s_it = it; s_local = local;
    lpout[bi] = (c==0) ? -1000.0f : wvv[bi];
  }
  __syncthreads();
  int q = s_q, c = wc[bi], it = s_it;
  const int*   bss = (t&1)? p.bs1 : p.bs0;   int*   bsd = (t&1)? p.bs0 : p.bs1;
  const float* lps = (t&1)? p.blp1: p.blp0;  float* lpd = (t&1)? p.blp0: p.blp1;
  if (tid < t){ bsd[tid*NB+bi] = bss[tid*NB+q]; lpd[tid*NB+bi] = lps[tid*NB+q]; }
  if (tid == t){ bsd[t*NB+bi] = c; lpd[t*NB+bi] = s_local; }
  const float* ms = (t==0) ? p.pnt : ((t&1)? p.mask1 : p.mask0);
  float* md = (t&1)? p.mask0 : p.mask1;
  if (tid < RP1){
    float m = ms[q*RP1 + tid];
    if (tid == 0) m = 0.f;
    if (c > NV && tid == (c - VP1) + 1) m = 1.0f;
    msk[tid] = m; md[bi*RP1 + tid] = m;
  }
  const float* hprev = (t==0) ? p.h0 : p.hst;
  float hv = hprev[(size_t)q*ND + tid];
  hhs[tid] = hv;
  p.hhgT[tid*NB + bi] = hv;
  p.xtT[tid*NB + bi] = p.embed[(size_t)it*ND + tid];
  if (tid >= 100 && tid < 128) att[tid] = -INFINITY;
  __syncthreads();
  // attention
  int w = tid >> 6, l = tid & 63;
  const float4* hh4 = reinterpret_cast<const float4*>(hhs);
  for (int r=w; r<NR; r+=16){
    const float4* pf4 = reinterpret_cast<const float4*>(p.pool + ((size_t)bi*NR + r)*ND);
    float s = 0.f;
    #pragma unroll
    for (int cc=0;cc<4;++cc){
      float4 pv = pf4[cc*64 + l];
      float4 hvv = hh4[cc*64 + l];
      s = fmaf(pv.x,hvv.x,s); s = fmaf(pv.y,hvv.y,s);
      s = fmaf(pv.z,hvv.z,s); s = fmaf(pv.w,hvv.w,s);
    }
    #pragma unroll
    for (int off=32; off; off>>=1) s += __shfl_down(s, off);
    if (l == 0) att[r] = (msk[r+1] > 0.f) ? NEGF : s*0.03125f;
  }
  __syncthreads();
  if (tid < 64){
    float a = att[tid], a2 = att[tid+64];
    float m = fmaxf(a, a2);
    #pragma unroll
    for (int off=32; off; off>>=1) m = fmaxf(m, __shfl_down(m, off));
    m = __shfl(m, 0);
    float e1 = expf(a - m);
    float e2 = expf(a2 - m);
    float s = e1 + e2;
    #pragma unroll
    for (int off=32; off; off>>=1) s += __shfl_down(s, off);
    s = __shfl(s, 0);
    att[tid] = e1 / s;
    att[tid+64] = e2 / s;
  }
  __syncthreads();
  float cx = 0.f;
  const float* pb = p.pool + (size_t)bi*NR*ND + tid;
  #pragma unroll 4
  for (int r=0;r<NR;++r) cx = fmaf(att[r], pb[(size_t)r*ND], cx);
  p.ctxT[tid*NB + bi] = cx;
}

// ------ K5: fused 3-matrix RNN GEMM partials (256 blocks = 4 jb x 64 ks) -----
__global__ __launch_bounds__(256) void k5_rnn(const float* __restrict__ Wx,
    const float* __restrict__ Wh, const float* __restrict__ Wc,
    const float* __restrict__ xtT, const float* __restrict__ hhgT,
    const float* __restrict__ ctxT, float* __restrict__ part){
  int tid = threadIdx.x;
  int jb = blockIdx.x & 3, ks = blockIdx.x >> 2;
  int j = jb*256 + tid;
  int k0 = ks*16;
  float acc[16];
  #pragma unroll
  for (int b=0;b<16;++b) acc[b]=0.f;
  for (int k=k0;k<k0+16;++k){
    float wx = Wx[(size_t)k*ND + j];
    float wh = Wh[(size_t)k*ND + j];
    float wc = Wc[(size_t)k*ND + j];
    const float4* xv = reinterpret_cast<const float4*>(xtT)  + (size_t)k*4;
    const float4* hv = reinterpret_cast<const float4*>(hhgT) + (size_t)k*4;
    const float4* cv = reinterpret_cast<const float4*>(ctxT) + (size_t)k*4;
    float4 x0=xv[0],x1=xv[1],x2=xv[2],x3=xv[3];
    float4 h0=hv[0],h1=hv[1],h2=hv[2],h3=hv[3];
    float4 c0=cv[0],c1=cv[1],c2=cv[2],c3=cv[3];
    acc[0]=fmaf(x0.x,wx,fmaf(h0.x,wh,fmaf(c0.x,wc,acc[0])));
    acc[1]=fmaf(x0.y,wx,fmaf(h0.y,wh,fmaf(c0.y,wc,acc[1])));
    acc[2]=fmaf(x0.z,wx,fmaf(h0.z,wh,fmaf(c0.z,wc,acc[2])));
    acc[3]=fmaf(x0.w,wx,fmaf(h0.w,wh,fmaf(c0.w,wc,acc[3])));
    acc[4]=fmaf(x1.x,wx,fmaf(h1.x,wh,fmaf(c1.x,wc,acc[4])));
    acc[5]=fmaf(x1.y,wx,fmaf(h1.y,wh,fmaf(c1.y,wc,acc[5])));
    acc[6]=fmaf(x1.z,wx,fmaf(h1.z,wh,fmaf(c1.z,wc,acc[6])));
    acc[7]=fmaf(x1.w,wx,fmaf(h1.w,wh,fmaf(c1.w,wc,acc[7])));
    acc[8]=fmaf(x2.x,wx,fmaf(h2.x,wh,fmaf(c2.x,wc,acc[8])));
    acc[9]=fmaf(x2.y,wx,fmaf(h2.y,wh,fmaf(c2.y,wc,acc[9])));
    acc[10]=fmaf(x2.z,wx,fmaf(h2.z,wh,fmaf(c2.z,wc,acc[10])));
    acc[11]=fmaf(x2.w,wx,fmaf(h2.w,wh,fmaf(c2.w,wc,acc[11])));
    acc[12]=fmaf(x3.x,wx,fmaf(h3.x,wh,fmaf(c3.x,wc,acc[12])));
    acc[13]=fmaf(x3.y,wx,fmaf(h3.y,wh,fmaf(c3.y,wc,acc[13])));
    acc[14]=fmaf(x3.z,wx,fmaf(h3.z,wh,fmaf(c3.z,wc,acc[14])));
    acc[15]=fmaf(x3.w,wx,fmaf(h3.w,wh,fmaf(c3.w,wc,acc[15])));
  }
  #pragma unroll
  for (int b=0;b<16;++b) part[((size_t)ks*16 + b)*ND + j] = acc[b];
}

// ---------------- K6: reduce 64 partials + tanh -> h_new ----------------
__global__ __launch_bounds__(256) void k6_tanh(P p){
  int o = blockIdx.x*256 + threadIdx.x;
  int b = o >> 10, j = o & 1023;
  float s = 0.f;
  for (int ks=0; ks<K5SPLIT; ++ks) s += p.part[((size_t)ks*16 + b)*ND + j];
  float hv = tanhf(s);
  p.hst[o] = hv;
  p.rnnT[j*NB + b] = hv;
}

// ---------------- K7: pack outputs (f32) ----------------
__global__ __launch_bounds__(256) void k7_out(P p, float* out){
  int i = blockIdx.x*256 + threadIdx.x;
  if (i < NT*NB)            out[i] = (float)p.bs0[i];
  else if (i < 2*NT*NB)     out[i] = p.blp0[i - NT*NB];
  else if (i < 2*NT*NB+NB)  out[i] = p.lp0[i - 2*NT*NB];
}

// ---------------- host ----------------
extern "C" void kernel_launch(void* const* d_in, const int* in_sizes, int n_in,
                              void* d_out, int out_size, void* d_ws, size_t ws_size,
                              hipStream_t stream) {
  P p;
  p.embed = (const float*)d_in[0];
  p.Wx    = (const float*)d_in[1];
  p.Wh    = (const float*)d_in[2];
  p.Wc    = (const float*)d_in[3];
  p.Wl    = (const float*)d_in[4];
  p.Wd    = (const float*)d_in[5];
  p.rnn0  = (const float*)d_in[6];
  p.det0  = (const float*)d_in[7];
  p.h0    = (const float*)d_in[8];
  p.pool  = (const float*)d_in[9];
  p.ppls  = (const float*)d_in[10];
  p.pnt   = (const float*)d_in[11];

  char* ws = (char*)d_ws;
  size_t off = 0;
  auto A = [&](size_t nfloats)->void* {
    void* r = ws + off;
    off += ((nfloats*4) + 255) & ~(size_t)255;
    return r;
  };
  p.WlP    = (float*)A((size_t)ND*VPAD);
  p.partL  = (float*)A((size_t)KS1*NB*VPAD);
  p.logits = (float*)A((size_t)NB*VP1R);
  p.dlp    = (float*)A(NB*RP1);
  p.rnnT   = (float*)A(ND*NB);
  p.hst    = (float*)A(NB*ND);
  p.hhgT   = (float*)A(ND*NB);
  p.xtT    = (float*)A(ND*NB);
  p.ctxT   = (float*)A(ND*NB);
  p.mask0  = (float*)A(NB*RP1);
  p.mask1  = (float*)A(NB*RP1);
  p.bs0    = (int*)A(NT*NB);
  p.bs1    = (int*)A(NT*NB);
  p.blp0   = (float*)A(NT*NB);
  p.blp1   = (float*)A(NT*NB);
  p.lp0    = (float*)A(NB);
  p.lp1    = (float*)A(NB);
  p.pkv    = (float*)A(EN_WORD);
  p.pkf    = (unsigned*)A(EN_WORD);
  p.part   = (float*)A((size_t)K5SPLIT*NB*ND);
  p.blkM   = (float*)A(NB*LSE_T);
  p.blkS   = (float*)A(NB*LSE_T);
  if (off > ws_size) return;

  k0_init<<<64,256,0,stream>>>(p);
  k0_pad<<<2048,256,0,stream>>>(p.Wl, p.WlP);
  for (int t=0; t<NT; ++t){
    k1_logits<<<dim3(KS1,49),256,0,stream>>>(p.WlP, p.rnnT, p.partL);
    k2_sum_topk<<<dim3(NSLICE,NB),256,0,stream>>>(p, t);
    k4_beam<<<NB,1024,0,stream>>>(p, t);
    k5_rnn<<<256,256,0,stream>>>(p.Wx, p.Wh, p.Wc, p.xtT, p.hhgT, p.ctxT, p.part);
    k6_tanh<<<64,256,0,stream>>>(p);
  }
  k7_out<<<3,256,0,stream>>>(p, (float*)d_out);
}

// Round 12
// 2909.972 us; speedup vs baseline: 1.1568x; 1.1568x over previous
//
#include <hip/hip_runtime.h>
#include <math.h>

#define NB 16
#define NR 100
#define NV 50000
#define ND 1024
#define NT 20
#define VP1 50001
#define VP1R 50004     // logits row stride (float4-aligned)
#define NJT 49         // j-tiles of 1024
#define VPAD (NJT*1024)  // 50176 padded col count
#define F4ROW (VPAD/4)   // 12544
#define VTT 50101
#define RP1 101
#define NEGF (-1e10f)
#define NSLICE 13      // 13*4096 >= VTT
#define LSE_TILES 49
#define KS1 8          // k1 k-groups (128 k each)
#define K5SPLIT 64
#define MERGE_N (NSLICE*NB*16)   // 3328

struct P {
  const float* embed; const float* Wx; const float* Wh; const float* Wc;
  const float* Wl; const float* Wd; const float* rnn0; const float* det0;
  const float* h0; const float* pool; const float* ppls; const float* pnt;
  float* WlT;      // [NJT][1024][1024] tile-major padded Wl
  float* logits;   // [16][VP1R]
  float* lse;      // [16]
  float* dlp;      // [16][101]
  float* rnnT;     // [1024][16]
  float* hst;      // [16][1024]
  float* hhgT;     // [1024][16]
  float* xtT;      // [1024][16]
  float* ctxT;     // [1024][16]
  float* mask0; float* mask1;       // [16][101] ping-pong
  int* bs0; int* bs1;               // [20][16] ping-pong
  float* blp0; float* blp1;         // [20][16] ping-pong
  float* lpsum;    // [16]
  float* pkv; unsigned* pkf;        // [MERGE_N]
  float* part;     // [K5SPLIT][16][1024]
  float* partL;    // [KS1][16][VPAD]
  float* blkM; float* blkS;         // [16*49]
};

__device__ __forceinline__ bool better(float av, unsigned af, float bv, unsigned bf){
  return (av > bv) || (av == bv && af < bf);
}
__device__ __forceinline__ void lsecomb(float& m, float& s, float m2, float s2){
  float M = fmaxf(m, m2);
  if (M == -INFINITY){ m = M; s = 0.f; return; }
  s = s*expf(m - M) + s2*expf(m2 - M);
  m = M;
}

// ---------------- K0: init ----------------
__global__ __launch_bounds__(256) void k0_init(P p){
  int i = blockIdx.x*256 + threadIdx.x;
  int n = gridDim.x*256;
  for (int o=i; o<NB*ND; o+=n){ int b=o>>10, k=o&1023; p.rnnT[k*NB+b] = p.rnn0[o]; }
  for (int o=i; o<NT*NB; o+=n){ p.bs0[o]=0; p.bs1[o]=0; p.blp0[o]=0.f; p.blp1[o]=0.f; }
  for (int o=i; o<NB; o+=n) p.lpsum[o]=0.f;
}

// ------- K0b: Wl -> WlT tile-major [jt][k][1024] (both sides coalesced) -----
__global__ __launch_bounds__(256) void k0_pad(const float* __restrict__ Wl,
                                              float* __restrict__ WlT){
  const int TOT = NJT * ND * 256;       // dst float4 count
  int idx0 = blockIdx.x*256 + threadIdx.x;
  int stride = gridDim.x*256;
  float4* dst = reinterpret_cast<float4*>(WlT);
  for (int idx = idx0; idx < TOT; idx += stride){
    int jt = idx / (ND*256);
    int r  = idx - jt*(ND*256);
    int k  = r >> 8;
    int q  = r & 255;
    int j  = jt*1024 + q*4;
    const float* src = Wl + (size_t)k*VP1 + j;
    float4 v;
    v.x = (j   < VP1) ? src[0] : 0.f;
    v.y = (j+1 < VP1) ? src[1] : 0.f;
    v.z = (j+2 < VP1) ? src[2] : 0.f;
    v.w = (j+3 < VP1) ? src[3] : 0.f;
    dst[idx] = v;
  }
}

// ---------------- K1: partial logits = rnn_out @ WlT ----------------
// grid (8, 49) x 256 thr. Each block streams a CONTIGUOUS 512 KB chunk of
// WlT ([jt][k0..k0+128)[1024 cols]); one float4 col-group per thread;
// 8-deep double-buffered batches (8 KB in flight/wave); 8 KB LDS rnnT slice.
__global__ __launch_bounds__(256) void k1_logits(const float* __restrict__ WlT,
    const float* __restrict__ rnnT, float* __restrict__ partL){
  __shared__ float rlds[128*16];     // 8 KB
  int tid = threadIdx.x;
  int g = blockIdx.x;                // 0..7
  int jt = blockIdx.y;               // 0..48
  int k0 = g*128;
  const float4* r4 = reinterpret_cast<const float4*>(rnnT) + (size_t)k0*4;
  float4* l4 = reinterpret_cast<float4*>(rlds);
  l4[tid] = r4[tid];
  l4[256+tid] = r4[256+tid];
  __syncthreads();
  const float4* wt = reinterpret_cast<const float4*>(WlT)
                   + ((size_t)jt*ND + k0)*256 + tid;   // per-k stride = 256 f4
  float4 acc[16];
  #pragma unroll
  for (int b=0;b<16;++b) acc[b] = make_float4(0.f,0.f,0.f,0.f);
  float4 wa[8], wb[8];
  #define LD8T(karr, kb) { \
    _Pragma("unroll") \
    for (int u=0;u<8;++u) karr[u] = wt[(size_t)((kb)+u)*256]; \
    }
  #define FMA8T(karr, kb) { \
    _Pragma("unroll") \
    for (int u=0;u<8;++u){ \
      const float* rr = &rlds[((kb)+u)*16]; \
      float4 wv = karr[u]; \
      _Pragma("unroll") \
      for (int b=0;b<16;++b){ \
        float r = rr[b]; \
        acc[b].x = fmaf(r, wv.x, acc[b].x); \
        acc[b].y = fmaf(r, wv.y, acc[b].y); \
        acc[b].z = fmaf(r, wv.z, acc[b].z); \
        acc[b].w = fmaf(r, wv.w, acc[b].w); \
      } \
    } }
  LD8T(wa, 0);
  #pragma unroll 1
  for (int bt=0; bt<8; ++bt){
    LD8T(wb, bt*16+8);
    FMA8T(wa, bt*16);
    if (bt < 7){ LD8T(wa, bt*16+16); }
    FMA8T(wb, bt*16+8);
  }
  #undef LD8T
  #undef FMA8T
  float4* pb = reinterpret_cast<float4*>(partL)
             + (size_t)(g*16)*F4ROW + jt*256 + tid;
  #pragma unroll
  for (int b=0;b<16;++b) pb[(size_t)b*F4ROW] = acc[b];
}

// -------- K2a: sum 8 k-partials -> logits + per-tile online LSE (49x16) ------
__global__ __launch_bounds__(256) void k2a_sum_lse(const float* __restrict__ partL,
    float* __restrict__ logits, float* __restrict__ blkM, float* __restrict__ blkS){
  int tile = blockIdx.x, b = blockIdx.y, tid = threadIdx.x;
  int j0 = tile*1024 + tid*4;
  float m = -INFINITY, s = 0.f;
  if (j0 < VP1){
    const float4* base = reinterpret_cast<const float4*>(partL);
    size_t jq = (size_t)(j0 >> 2);
    float4 sm4 = make_float4(0.f,0.f,0.f,0.f);
    #pragma unroll
    for (int g=0; g<KS1; ++g){
      float4 a = base[(size_t)(g*16+b)*F4ROW + jq];
      sm4.x += a.x; sm4.y += a.y; sm4.z += a.z; sm4.w += a.w;
    }
    reinterpret_cast<float4*>(logits)[(size_t)b*(VP1R/4) + jq] = sm4;
    float vals[4] = {sm4.x, sm4.y, sm4.z, sm4.w};
    #pragma unroll
    for (int e=0;e<4;++e){
      if (j0+e < VP1){
        float x = vals[e];
        if (x > m){ s = s*expf(m-x) + 1.f; m = x; }
        else s += expf(x-m);
      }
    }
  }
  #pragma unroll
  for (int off=32; off; off>>=1){
    float m2 = __shfl_down(m, off), s2 = __shfl_down(s, off);
    lsecomb(m, s, m2, s2);
  }
  __shared__ float wm[4], ws2[4];
  int w = tid >> 6;
  if ((tid & 63) == 0){ wm[w] = m; ws2[w] = s; }
  __syncthreads();
  if (tid == 0){
    float M = wm[0], S = ws2[0];
    lsecomb(M, S, wm[1], ws2[1]);
    lsecomb(M, S, wm[2], ws2[2]);
    lsecomb(M, S, wm[3], ws2[3]);
    blkM[b*LSE_TILES + tile] = M; blkS[b*LSE_TILES + tile] = S;
  }
}

// ---------------- K2b: lse combine (blocks 0-15) + det head (blocks 16-31) ---
__global__ __launch_bounds__(512) void k2b_lse_det(P p, int t){
  int bx = blockIdx.x, tid = threadIdx.x;
  if (bx < 16){
    if (tid < 64){
      int b = bx;
      float m = -INFINITY, s = 0.f;
      if (tid < LSE_TILES){ m = p.blkM[b*LSE_TILES + tid]; s = p.blkS[b*LSE_TILES + tid]; }
      #pragma unroll
      for (int off=32; off; off>>=1){
        float m2 = __shfl_down(m, off), s2 = __shfl_down(s, off);
        lsecomb(m, s, m2, s2);
      }
      if (tid == 0) p.lse[b] = m + logf(s);
    }
    return;
  }
  int b = bx - 16;
  __shared__ float dred[4][129];
  __shared__ float ddet[128];
  int jj = tid & 127, ks = tid >> 7;
  if (t == 0){
    if (tid < 128) ddet[tid] = (tid < RP1) ? p.det0[b*RP1 + tid] : -INFINITY;
    __syncthreads();
  } else {
    float a = 0.f;
    if (jj < RP1){
      const float* hr = p.hst + b*ND;
      for (int k=ks*256; k<ks*256+256; ++k)
        a = fmaf(hr[k], p.Wd[(size_t)k*RP1 + jj], a);
    }
    dred[ks][jj] = a;
    __syncthreads();
    if (tid < 128)
      ddet[tid] = (tid < RP1) ? (dred[0][tid]+dred[1][tid]+dred[2][tid]+dred[3][tid]) : -INFINITY;
    __syncthreads();
  }
  if (tid < 64){
    float a = ddet[tid], a2 = ddet[tid+64];
    float m = fmaxf(a, a2);
    #pragma unroll
    for (int off=32; off; off>>=1) m = fmaxf(m, __shfl_down(m, off));
    m = __shfl(m, 0);
    float e1 = (tid < RP1) ? expf(a - m) : 0.f;
    float e2 = (tid+64 < RP1) ? expf(a2 - m) : 0.f;
    float s = e1 + e2;
    #pragma unroll
    for (int off=32; off; off>>=1) s += __shfl_down(s, off);
    s = __shfl(s, 0);
    float ls = logf(s);
    if (tid < RP1)     p.dlp[b*RP1 + tid]      = a  - m - ls;
    if (tid+64 < RP1)  p.dlp[b*RP1 + tid + 64] = a2 - m - ls;
  }
}

// ------- K3: candidates + per-block top16 (13 slices x 16 beams) -------------
__global__ __launch_bounds__(256) void k3_cand(P p, int t){
  int tid = threadIdx.x;
  int slice = blockIdx.x, b = blockIdx.y;
  float lv[16]; unsigned lf[16];
  float cA = p.lpsum[b] - p.lse[b] + p.dlp[b*RP1];
  float cB = p.lpsum[b];
  bool dead = (t==0 && b>0);
  const float* lrow = p.logits + (size_t)b*VP1R;
  const float* drow = p.dlp + b*RP1;
  unsigned fbase = (unsigned)(b*VTT);
  int j0 = slice*4096 + (tid<<2);
  #pragma unroll
  for (int c=0;c<4;++c){
    int j = j0 + c*1024;
    bool vec = (j+4 <= VP1);
    float4 lg = make_float4(0.f,0.f,0.f,0.f);
    if (vec) lg = *reinterpret_cast<const float4*>(lrow + j);
    float le[4] = {lg.x, lg.y, lg.z, lg.w};
    #pragma unroll
    for (int e=0;e<4;++e){
      int jj = j + e;
      float v; unsigned f;
      if (jj < VP1){ v = cA + (vec ? le[e] : lrow[jj]); f = fbase + (unsigned)jj; }
      else if (jj < VTT){ v = cB + drow[jj - NV]; f = fbase + (unsigned)jj; }
      else { v = -3e38f; f = 0xFFFFFFFFu; }
      if (dead && f != 0xFFFFFFFFu) v = NEGF;
      lv[c*4+e] = v; lf[c*4+e] = f;
    }
  }
  __shared__ float wmv[4]; __shared__ unsigned wmf[4];
  __shared__ unsigned sbf;
  int lane = tid & 63, wid = tid >> 6;
  int blin = b*NSLICE + slice;
  for (int r=0;r<16;++r){
    float bv = lv[0]; unsigned bf = lf[0];
    #pragma unroll
    for (int u=1;u<16;++u) if (better(lv[u],lf[u],bv,bf)){ bv=lv[u]; bf=lf[u]; }
    #pragma unroll
    for (int off=32; off; off>>=1){
      float ov = __shfl_down(bv, off); unsigned of = __shfl_down(bf, off);
      if (better(ov,of,bv,bf)){ bv=ov; bf=of; }
    }
    if (lane==0){ wmv[wid]=bv; wmf[wid]=bf; }
    __syncthreads();
    if (tid==0){
      float mv2=wmv[0]; unsigned mf2=wmf[0];
      #pragma unroll
      for (int w=1;w<4;++w) if (better(wmv[w],wmf[w],mv2,mf2)){ mv2=wmv[w]; mf2=wmf[w]; }
      p.pkv[blin*16+r]=mv2; p.pkf[blin*16+r]=mf2;
      sbf=mf2;
    }
    __syncthreads();
    unsigned WF = sbf;
    #pragma unroll
    for (int u=0;u<16;++u) if (lf[u]==WF){ lv[u]=-3e38f; lf[u]=0xFFFFFFFFu; }
  }
}

// ------- K4: redundant global merge + per-beam state + attention (16x1024) ---
__global__ __launch_bounds__(1024) void k4_beam(P p, int t){
  int bi = blockIdx.x, tid = threadIdx.x;
  float ev[4]; unsigned ef[4];
  #pragma unroll
  for (int c=0;c<4;++c){
    int idx = c*1024 + tid;
    if (idx < MERGE_N){ ev[c]=p.pkv[idx]; ef[c]=p.pkf[idx]; }
    else { ev[c]=-3e38f; ef[c]=0xFFFFFFFFu; }
  }
  __shared__ float wmv[16]; __shared__ unsigned wmf[16];
  __shared__ unsigned sbf;
  __shared__ int wq[16], wc[16]; __shared__ float wvv[16];
  __shared__ float hhs[ND];
  __shared__ float att[128];
  __shared__ float msk[RP1];
  __shared__ int s_q, s_it; __shared__ float s_local;
  int lane = tid & 63, wid = tid >> 6;
  for (int r=0;r<16;++r){
    float bv = ev[0]; unsigned bf = ef[0];
    #pragma unroll
    for (int c=1;c<4;++c) if (better(ev[c],ef[c],bv,bf)){ bv=ev[c]; bf=ef[c]; }
    #pragma unroll
    for (int off=32; off; off>>=1){
      float ov = __shfl_down(bv, off); unsigned of = __shfl_down(bf, off);
      if (better(ov,of,bv,bf)){ bv=ov; bf=of; }
    }
    if (lane==0){ wmv[wid]=bv; wmf[wid]=bf; }
    __syncthreads();
    if (tid==0){
      float mv2=wmv[0]; unsigned mf2=wmf[0];
      #pragma unroll
      for (int w=1;w<16;++w) if (better(wmv[w],wmf[w],mv2,mf2)){ mv2=wmv[w]; mf2=wmf[w]; }
      unsigned q = mf2 / VTT; unsigned c = mf2 - q*VTT;
      wq[r]=(int)q; wc[r]=(int)c; wvv[r]=mv2;
      sbf=mf2;
    }
    __syncthreads();
    unsigned WF = sbf;
    #pragma unroll
    for (int c=0;c<4;++c) if (ef[c]==WF){ ev[c]=-3e38f; ef[c]=0xFFFFFFFFu; }
  }
  if (tid == 0){
    int q = wq[bi], c = wc[bi];
    float local = (c < VP1) ? (p.logits[(size_t)q*VP1R + c] - p.lse[q] + p.dlp[q*RP1])
                            : p.dlp[q*RP1 + (c - NV)];
    int it = (c > NV) ? ((int)p.ppls[((size_t)bi*NR + (c - VP1))*6 + 4] + NV) : c;
    s_q = q; s_it = it; s_local = local;
    p.lpsum[bi] = (c==0) ? -1000.0f : wvv[bi];
  }
  __syncthreads();
  int q = s_q, c = wc[bi], it = s_it;
  const int*   bss = (t&1)? p.bs1 : p.bs0;   int*   bsd = (t&1)? p.bs0 : p.bs1;
  const float* lps = (t&1)? p.blp1: p.blp0;  float* lpd = (t&1)? p.blp0: p.blp1;
  if (tid < t){ bsd[tid*NB+bi] = bss[tid*NB+q]; lpd[tid*NB+bi] = lps[tid*NB+q]; }
  if (tid == t){ bsd[t*NB+bi] = c; lpd[t*NB+bi] = s_local; }
  const float* ms = (t==0) ? p.pnt : ((t&1)? p.mask1 : p.mask0);
  float* md = (t&1)? p.mask0 : p.mask1;
  if (tid < RP1){
    float m = ms[q*RP1 + tid];
    if (tid == 0) m = 0.f;
    if (c > NV && tid == (c - VP1) + 1) m = 1.0f;
    msk[tid] = m; md[bi*RP1 + tid] = m;
  }
  const float* hprev = (t==0) ? p.h0 : p.hst;
  float hv = hprev[(size_t)q*ND + tid];
  hhs[tid] = hv;
  p.hhgT[tid*NB + bi] = hv;
  p.xtT[tid*NB + bi] = p.embed[(size_t)it*ND + tid];
  if (tid >= 100 && tid < 128) att[tid] = -INFINITY;
  __syncthreads();
  int w = tid >> 6, l = tid & 63;
  const float4* hh4 = reinterpret_cast<const float4*>(hhs);
  for (int r=w; r<NR; r+=16){
    const float4* pf4 = reinterpret_cast<const float4*>(p.pool + ((size_t)bi*NR + r)*ND);
    float s = 0.f;
    #pragma unroll
    for (int cc=0;cc<4;++cc){
      float4 pv = pf4[cc*64 + l];
      float4 hvv = hh4[cc*64 + l];
      s = fmaf(pv.x,hvv.x,s); s = fmaf(pv.y,hvv.y,s);
      s = fmaf(pv.z,hvv.z,s); s = fmaf(pv.w,hvv.w,s);
    }
    #pragma unroll
    for (int off=32; off; off>>=1) s += __shfl_down(s, off);
    if (l == 0) att[r] = (msk[r+1] > 0.f) ? NEGF : s*0.03125f;
  }
  __syncthreads();
  if (tid < 64){
    float a = att[tid], a2 = att[tid+64];
    float m = fmaxf(a, a2);
    #pragma unroll
    for (int off=32; off; off>>=1) m = fmaxf(m, __shfl_down(m, off));
    m = __shfl(m, 0);
    float e1 = expf(a - m);
    float e2 = expf(a2 - m);
    float s = e1 + e2;
    #pragma unroll
    for (int off=32; off; off>>=1) s += __shfl_down(s, off);
    s = __shfl(s, 0);
    att[tid] = e1 / s;
    att[tid+64] = e2 / s;
  }
  __syncthreads();
  float cx = 0.f;
  const float* pb = p.pool + (size_t)bi*NR*ND + tid;
  #pragma unroll 4
  for (int r=0;r<NR;++r) cx = fmaf(att[r], pb[(size_t)r*ND], cx);
  p.ctxT[tid*NB + bi] = cx;
}

// ------ K5: fused 3-matrix RNN GEMM partials (256 blocks = 4 jb x 64 ks) -----
__global__ __launch_bounds__(256) void k5_rnn(const float* __restrict__ Wx,
    const float* __restrict__ Wh, const float* __restrict__ Wc,
    const float* __restrict__ xtT, const float* __restrict__ hhgT,
    const float* __restrict__ ctxT, float* __restrict__ part){
  int tid = threadIdx.x;
  int jb = blockIdx.x & 3, ks = blockIdx.x >> 2;
  int j = jb*256 + tid;
  int k0 = ks*16;
  float acc[16];
  #pragma unroll
  for (int b=0;b<16;++b) acc[b]=0.f;
  for (int k=k0;k<k0+16;++k){
    float wx = Wx[(size_t)k*ND + j];
    float wh = Wh[(size_t)k*ND + j];
    float wc = Wc[(size_t)k*ND + j];
    const float4* xv = reinterpret_cast<const float4*>(xtT)  + (size_t)k*4;
    const float4* hv = reinterpret_cast<const float4*>(hhgT) + (size_t)k*4;
    const float4* cv = reinterpret_cast<const float4*>(ctxT) + (size_t)k*4;
    float4 x0=xv[0],x1=xv[1],x2=xv[2],x3=xv[3];
    float4 h0=hv[0],h1=hv[1],h2=hv[2],h3=hv[3];
    float4 c0=cv[0],c1=cv[1],c2=cv[2],c3=cv[3];
    acc[0]=fmaf(x0.x,wx,fmaf(h0.x,wh,fmaf(c0.x,wc,acc[0])));
    acc[1]=fmaf(x0.y,wx,fmaf(h0.y,wh,fmaf(c0.y,wc,acc[1])));
    acc[2]=fmaf(x0.z,wx,fmaf(h0.z,wh,fmaf(c0.z,wc,acc[2])));
    acc[3]=fmaf(x0.w,wx,fmaf(h0.w,wh,fmaf(c0.w,wc,acc[3])));
    acc[4]=fmaf(x1.x,wx,fmaf(h1.x,wh,fmaf(c1.x,wc,acc[4])));
    acc[5]=fmaf(x1.y,wx,fmaf(h1.y,wh,fmaf(c1.y,wc,acc[5])));
    acc[6]=fmaf(x1.z,wx,fmaf(h1.z,wh,fmaf(c1.z,wc,acc[6])));
    acc[7]=fmaf(x1.w,wx,fmaf(h1.w,wh,fmaf(c1.w,wc,acc[7])));
    acc[8]=fmaf(x2.x,wx,fmaf(h2.x,wh,fmaf(c2.x,wc,acc[8])));
    acc[9]=fmaf(x2.y,wx,fmaf(h2.y,wh,fmaf(c2.y,wc,acc[9])));
    acc[10]=fmaf(x2.z,wx,fmaf(h2.z,wh,fmaf(c2.z,wc,acc[10])));
    acc[11]=fmaf(x2.w,wx,fmaf(h2.w,wh,fmaf(c2.w,wc,acc[11])));
    acc[12]=fmaf(x3.x,wx,fmaf(h3.x,wh,fmaf(c3.x,wc,acc[12])));
    acc[13]=fmaf(x3.y,wx,fmaf(h3.y,wh,fmaf(c3.y,wc,acc[13])));
    acc[14]=fmaf(x3.z,wx,fmaf(h3.z,wh,fmaf(c3.z,wc,acc[14])));
    acc[15]=fmaf(x3.w,wx,fmaf(h3.w,wh,fmaf(c3.w,wc,acc[15])));
  }
  #pragma unroll
  for (int b=0;b<16;++b) part[((size_t)ks*16 + b)*ND + j] = acc[b];
}

// ---------------- K6: reduce 64 partials + tanh -> h_new ----------------
__global__ __launch_bounds__(256) void k6_tanh(P p){
  int o = blockIdx.x*256 + threadIdx.x;
  int b = o >> 10, j = o & 1023;
  float s = 0.f;
  for (int ks=0; ks<K5SPLIT; ++ks) s += p.part[((size_t)ks*16 + b)*ND + j];
  float hv = tanhf(s);
  p.hst[o] = hv;
  p.rnnT[j*NB + b] = hv;
}

// ---------------- K7: pack outputs (f32) ----------------
__global__ __launch_bounds__(256) void k7_out(P p, float* out){
  int i = blockIdx.x*256 + threadIdx.x;
  if (i < NT*NB)            out[i] = (float)p.bs0[i];
  else if (i < 2*NT*NB)     out[i] = p.blp0[i - NT*NB];
  else if (i < 2*NT*NB+NB)  out[i] = p.lpsum[i - 2*NT*NB];
}

// ---------------- host ----------------
extern "C" void kernel_launch(void* const* d_in, const int* in_sizes, int n_in,
                              void* d_out, int out_size, void* d_ws, size_t ws_size,
                              hipStream_t stream) {
  P p;
  p.embed = (const float*)d_in[0];
  p.Wx    = (const float*)d_in[1];
  p.Wh    = (const float*)d_in[2];
  p.Wc    = (const float*)d_in[3];
  p.Wl    = (const float*)d_in[4];
  p.Wd    = (const float*)d_in[5];
  p.rnn0  = (const float*)d_in[6];
  p.det0  = (const float*)d_in[7];
  p.h0    = (const float*)d_in[8];
  p.pool  = (const float*)d_in[9];
  p.ppls  = (const float*)d_in[10];
  p.pnt   = (const float*)d_in[11];

  char* ws = (char*)d_ws;
  size_t off = 0;
  auto A = [&](size_t nfloats)->void* {
    void* r = ws + off;
    off += ((nfloats*4) + 255) & ~(size_t)255;
    return r;
  };
  p.WlT    = (float*)A((size_t)NJT*ND*1024);
  p.partL  = (float*)A((size_t)KS1*NB*VPAD);
  p.logits = (float*)A((size_t)NB*VP1R);
  p.lse    = (float*)A(NB);
  p.dlp    = (float*)A(NB*RP1);
  p.rnnT   = (float*)A(ND*NB);
  p.hst    = (float*)A(NB*ND);
  p.hhgT   = (float*)A(ND*NB);
  p.xtT    = (float*)A(ND*NB);
  p.ctxT   = (float*)A(ND*NB);
  p.mask0  = (float*)A(NB*RP1);
  p.mask1  = (float*)A(NB*RP1);
  p.bs0    = (int*)A(NT*NB);
  p.bs1    = (int*)A(NT*NB);
  p.blp0   = (float*)A(NT*NB);
  p.blp1   = (float*)A(NT*NB);
  p.lpsum  = (float*)A(NB);
  p.pkv    = (float*)A(MERGE_N);
  p.pkf    = (unsigned*)A(MERGE_N);
  p.part   = (float*)A((size_t)K5SPLIT*NB*ND);
  p.blkM   = (float*)A(NB*LSE_TILES);
  p.blkS   = (float*)A(NB*LSE_TILES);
  if (off > ws_size) return;

  k0_init<<<64,256,0,stream>>>(p);
  k0_pad<<<2048,256,0,stream>>>(p.Wl, p.WlT);
  for (int t=0; t<NT; ++t){
    k1_logits<<<dim3(KS1,NJT),256,0,stream>>>(p.WlT, p.rnnT, p.partL);
    k2a_sum_lse<<<dim3(LSE_TILES,NB),256,0,stream>>>(p.partL, p.logits, p.blkM, p.blkS);
    k2b_lse_det<<<32,512,0,stream>>>(p, t);
    k3_cand<<<dim3(NSLICE,NB),256,0,stream>>>(p, t);
    k4_beam<<<NB,1024,0,stream>>>(p, t);
    k5_rnn<<<256,256,0,stream>>>(p.Wx, p.Wh, p.Wc, p.xtT, p.hhgT, p.ctxT, p.part);
    k6_tanh<<<64,256,0,stream>>>(p);
  }
  k7_out<<<3,256,0,stream>>>(p, (float*)d_out);
}